// Round 6
// baseline (261.386 us; speedup 1.0000x reference)
//
#include <hip/hip_runtime.h>
#include <math.h>

#define SEQ   2048
#define DM    1024
#define NH    16
#define DK    64
#define MTOT  4096
// q pre-scale: 1/sqrt(64) * log2(e), so softmax runs in exp2 domain
#define QSCALE 0.18033688011112043f

typedef __bf16 bf16x8 __attribute__((ext_vector_type(8)));
typedef float  f32x4  __attribute__((ext_vector_type(4)));
typedef unsigned short u16;
typedef unsigned long long u64;

// RNE float->bf16 (finite inputs)
__device__ __forceinline__ u16 f2bf(float f) {
    unsigned int u = __float_as_uint(f);
    u += 0x7fff + ((u >> 16) & 1);
    return (u16)(u >> 16);
}

// async global->LDS, 16B per lane; LDS dest = base + lane*16 (HW semantics)
__device__ __forceinline__ void async16(const void* g, void* l) {
    __builtin_amdgcn_global_load_lds(
        (const __attribute__((address_space(1))) unsigned int*)(unsigned long long)g,
        (__attribute__((address_space(3))) unsigned int*)(unsigned int)(unsigned long long)l,
        16, 0, 0);
}

// Alias-safe LDS accessors (memcpy => universal aliasing; same ds codegen)
__device__ __forceinline__ bf16x8 ld16(const u16* p) {        // 16B aligned
    bf16x8 v;
    __builtin_memcpy(&v, p, 16);
    return v;
}
__device__ __forceinline__ bf16x8 ld8x2(const u16* p) {       // 8B aligned
    union { u64 q[2]; bf16x8 v; } u;
    __builtin_memcpy(&u.q[0], p, 8);
    __builtin_memcpy(&u.q[1], p + 4, 8);
    return u.v;
}
__device__ __forceinline__ void st8(u16* p, unsigned int lo, unsigned int hi) {
    u64 q = ((u64)hi << 32) | lo;
    __builtin_memcpy(p, &q, 8);
}

// ---------------------------------------------------------------------------
// fp32 -> bf16 elementwise (Q, K, V inputs), 8 elems/thread
// ---------------------------------------------------------------------------
__global__ __launch_bounds__(256)
void cvt_in(const float* __restrict__ Q, const float* __restrict__ K,
            const float* __restrict__ V, u16* __restrict__ Qb,
            u16* __restrict__ Kb, u16* __restrict__ Vb)
{
    const float* src; u16* dst;
    if (blockIdx.z == 0)      { src = Q; dst = Qb; }
    else if (blockIdx.z == 1) { src = K; dst = Kb; }
    else                      { src = V; dst = Vb; }
    const size_t i = ((size_t)blockIdx.x * 256 + threadIdx.x) * 8;
    float4 a = *(const float4*)&src[i];
    float4 b = *(const float4*)&src[i + 4];
    uint4 o;
    o.x = (unsigned)f2bf(a.x) | ((unsigned)f2bf(a.y) << 16);
    o.y = (unsigned)f2bf(a.z) | ((unsigned)f2bf(a.w) << 16);
    o.z = (unsigned)f2bf(b.x) | ((unsigned)f2bf(b.y) << 16);
    o.w = (unsigned)f2bf(b.z) | ((unsigned)f2bf(b.w) << 16);
    *(uint4*)&dst[i] = o;
}

// ---------------------------------------------------------------------------
// W [k][n] fp32 -> Wt [n][k] bf16 (64x64 tiles via LDS)
// ---------------------------------------------------------------------------
__global__ __launch_bounds__(256)
void cvt_wt(const float* __restrict__ Wq, const float* __restrict__ Wk,
            const float* __restrict__ Wv, const float* __restrict__ Wo,
            u16* __restrict__ Tq, u16* __restrict__ Tk,
            u16* __restrict__ Tv, u16* __restrict__ To)
{
    const float* W; u16* Wt;
    if (blockIdx.z == 0)      { W = Wq; Wt = Tq; }
    else if (blockIdx.z == 1) { W = Wk; Wt = Tk; }
    else if (blockIdx.z == 2) { W = Wv; Wt = Tv; }
    else                      { W = Wo; Wt = To; }
    __shared__ float Ts[64][65];
    const int t = threadIdx.x;
    const int k0 = blockIdx.x * 64, n0 = blockIdx.y * 64;
#pragma unroll
    for (int p = 0; p < 4; ++p) {
        const int flat = t + p * 256;
        const int r = flat >> 4, c4 = (flat & 15) * 4;
        float4 v = *(const float4*)&W[(size_t)(k0 + r) * DM + n0 + c4];
        Ts[r][c4 + 0] = v.x; Ts[r][c4 + 1] = v.y;
        Ts[r][c4 + 2] = v.z; Ts[r][c4 + 3] = v.w;
    }
    __syncthreads();
#pragma unroll
    for (int p = 0; p < 2; ++p) {
        const int flat = t + p * 256;
        const int n = flat >> 3, kc = (flat & 7) * 8;
        uint4 o;
        o.x = (unsigned)f2bf(Ts[kc + 0][n]) | ((unsigned)f2bf(Ts[kc + 1][n]) << 16);
        o.y = (unsigned)f2bf(Ts[kc + 2][n]) | ((unsigned)f2bf(Ts[kc + 3][n]) << 16);
        o.z = (unsigned)f2bf(Ts[kc + 4][n]) | ((unsigned)f2bf(Ts[kc + 5][n]) << 16);
        o.w = (unsigned)f2bf(Ts[kc + 6][n]) | ((unsigned)f2bf(Ts[kc + 7][n]) << 16);
        *(uint4*)&Wt[(size_t)(n0 + n) * DM + k0 + kc] = o;
    }
}

// ---------------------------------------------------------------------------
// bf16 MFMA GEMM: C[m][n] = A[m][k] * Wt[n][k]^T + bias
// 128x128 tile, BK=64 (halved barrier count), 4 waves 2x2.
// SCATTER=1: bf16 out [bh][s][dk] (with scale); SCATTER=2: bf16 out
// [bh][dk][s] (transposed, 4 consecutive s packed per 8B store);
// SCATTER=0: fp32 out [m][n].
// ---------------------------------------------------------------------------
template <int SCATTER>
__device__ __forceinline__ void gemm_core(const u16* __restrict__ A,
                                          const u16* __restrict__ Wt,
                                          const float* __restrict__ bias,
                                          void* __restrict__ Out, float scale)
{
    __shared__ u16 As[128 * 64];   // 16 KB
    __shared__ u16 Bs[128 * 64];   // 16 KB

    const int tid = threadIdx.x;
    const int lane = tid & 63;
    const int wv = __builtin_amdgcn_readfirstlane(tid >> 6);
    const int wm = wv >> 1, wn = wv & 1;
    const int lane15 = lane & 15, quad = lane >> 4;
    const int row0 = blockIdx.x * 128, col0 = blockIdx.y * 128;

    const int arow = lane >> 3;          // 0..7
    const int acol = (lane & 7) * 8;     // bf16 col within 64

    f32x4 acc[4][4];
#pragma unroll
    for (int i = 0; i < 4; ++i)
#pragma unroll
        for (int j = 0; j < 4; ++j) acc[i][j] = (f32x4)0.f;

    for (int k0 = 0; k0 < DM; k0 += 64) {
#pragma unroll
        for (int cc = 0; cc < 4; ++cc) {
            const int c = 4 * wv + cc;           // chunk 0..15 = 8 rows each
            async16(&A[(size_t)(row0 + c * 8 + arow) * DM + k0 + acol],
                    &As[c * 512]);
            async16(&Wt[(size_t)(col0 + c * 8 + arow) * DM + k0 + acol],
                    &Bs[c * 512]);
        }
        __syncthreads();

#pragma unroll
        for (int kk = 0; kk < 2; ++kk) {
            bf16x8 af[4];
#pragma unroll
            for (int mi = 0; mi < 4; ++mi)
                af[mi] = ld16(&As[(wm * 64 + mi * 16 + lane15) * 64 +
                                  kk * 32 + quad * 8]);
#pragma unroll
            for (int ni = 0; ni < 4; ++ni) {
                bf16x8 bfrag = ld16(&Bs[(wn * 64 + ni * 16 + lane15) * 64 +
                                        kk * 32 + quad * 8]);
#pragma unroll
                for (int mi = 0; mi < 4; ++mi)
                    acc[mi][ni] = __builtin_amdgcn_mfma_f32_16x16x32_bf16(
                        af[mi], bfrag, acc[mi][ni], 0, 0, 0);
            }
        }
        __syncthreads();
    }

#pragma unroll
    for (int mi = 0; mi < 4; ++mi) {
        const int mbase = row0 + wm * 64 + mi * 16 + quad * 4;
#pragma unroll
        for (int ni = 0; ni < 4; ++ni) {
            const int n = col0 + wn * 64 + ni * 16 + lane15;
            const float bz = bias[n];
            if (SCATTER == 1) {
                const int h = n >> 6, dk = n & 63;
#pragma unroll
                for (int r = 0; r < 4; ++r) {
                    const int mm = mbase + r;
                    const int b_ = mm >> 11, s = mm & 2047;
                    ((u16*)Out)[(((size_t)(b_ * NH + h)) * SEQ + s) * DK + dk] =
                        f2bf((acc[mi][ni][r] + bz) * scale);
                }
            } else if (SCATTER == 2) {
                // transposed scatter: [bh][dk][s]; 4 consecutive s packed
                const int h = n >> 6, dk = n & 63;
                const int b_ = mbase >> 11, s0 = mbase & 2047;
                u64 q = (u64)f2bf((acc[mi][ni][0] + bz) * scale)
                      | ((u64)f2bf((acc[mi][ni][1] + bz) * scale) << 16)
                      | ((u64)f2bf((acc[mi][ni][2] + bz) * scale) << 32)
                      | ((u64)f2bf((acc[mi][ni][3] + bz) * scale) << 48);
                u16* dst = (u16*)Out +
                    (((size_t)(b_ * NH + h)) * DK + dk) * SEQ + s0;
                __builtin_memcpy(dst, &q, 8);
            } else {
#pragma unroll
                for (int r = 0; r < 4; ++r) {
                    const int mm = mbase + r;
                    ((float*)Out)[(size_t)mm * DM + n] = acc[mi][ni][r] + bz;
                }
            }
        }
    }
}

__global__ __launch_bounds__(256)
void qkv_gemm(const u16* __restrict__ Qb, const u16* __restrict__ Kb,
              const u16* __restrict__ Vb,
              const u16* __restrict__ Tq, const u16* __restrict__ Tk,
              const u16* __restrict__ Tv,
              const float* __restrict__ bq, const float* __restrict__ bk,
              const float* __restrict__ bv,
              u16* __restrict__ qw, u16* __restrict__ kw, u16* __restrict__ vtw)
{
    if (blockIdx.z == 0)      gemm_core<1>(Qb, Tq, bq, qw, QSCALE);
    else if (blockIdx.z == 1) gemm_core<1>(Kb, Tk, bk, kw, 1.0f);
    else                      gemm_core<2>(Vb, Tv, bv, vtw, 1.0f);
}

// ---------------------------------------------------------------------------
// Output GEMM: 128x64 tiles, BK=64. 512 blocks (2/CU).
// 4 waves as 2x2 over (128m x 64n); wave = 64m x 32n = 4x2 MFMA tiles.
// ---------------------------------------------------------------------------
__global__ __launch_bounds__(256)
void out_gemm(const u16* __restrict__ A, const u16* __restrict__ Wt,
              const float* __restrict__ bias, float* __restrict__ Out)
{
    __shared__ u16 As[128 * 64];
    __shared__ u16 Bs[64 * 64];

    const int tid = threadIdx.x;
    const int lane = tid & 63;
    const int wv = __builtin_amdgcn_readfirstlane(tid >> 6);
    const int wm = wv >> 1, wn = wv & 1;
    const int lane15 = lane & 15, quad = lane >> 4;
    const int row0 = blockIdx.x * 128, col0 = blockIdx.y * 64;

    const int arow = lane >> 3;
    const int acol = (lane & 7) * 8;

    f32x4 acc[4][2];
#pragma unroll
    for (int i = 0; i < 4; ++i)
#pragma unroll
        for (int j = 0; j < 2; ++j) acc[i][j] = (f32x4)0.f;

    for (int k0 = 0; k0 < DM; k0 += 64) {
#pragma unroll
        for (int cc = 0; cc < 4; ++cc) {
            const int c = 4 * wv + cc;
            async16(&A[(size_t)(row0 + c * 8 + arow) * DM + k0 + acol],
                    &As[c * 512]);
        }
#pragma unroll
        for (int cc = 0; cc < 2; ++cc) {
            const int c = 2 * wv + cc;
            async16(&Wt[(size_t)(col0 + c * 8 + arow) * DM + k0 + acol],
                    &Bs[c * 512]);
        }
        __syncthreads();

#pragma unroll
        for (int kk = 0; kk < 2; ++kk) {
            bf16x8 af[4];
#pragma unroll
            for (int mi = 0; mi < 4; ++mi)
                af[mi] = ld16(&As[(wm * 64 + mi * 16 + lane15) * 64 +
                                  kk * 32 + quad * 8]);
#pragma unroll
            for (int ni = 0; ni < 2; ++ni) {
                bf16x8 bfrag = ld16(&Bs[(wn * 32 + ni * 16 + lane15) * 64 +
                                        kk * 32 + quad * 8]);
#pragma unroll
                for (int mi = 0; mi < 4; ++mi)
                    acc[mi][ni] = __builtin_amdgcn_mfma_f32_16x16x32_bf16(
                        af[mi], bfrag, acc[mi][ni], 0, 0, 0);
            }
        }
        __syncthreads();
    }

#pragma unroll
    for (int mi = 0; mi < 4; ++mi) {
        const int mbase = row0 + wm * 64 + mi * 16 + quad * 4;
#pragma unroll
        for (int ni = 0; ni < 2; ++ni) {
            const int n = col0 + wn * 32 + ni * 16 + lane15;
            const float bz = bias[n];
#pragma unroll
            for (int r = 0; r < 4; ++r)
                Out[(size_t)(mbase + r) * DM + n] = acc[mi][ni][r] + bz;
        }
    }
}

// ---------------------------------------------------------------------------
// Flash attention, bf16 MFMA, linear softmax. Block = 4 waves x 16 q-rows
// = 64 q-rows; grid (bh=32, qtile=32) = 1024 blocks -> 4 blocks/CU.
// Register-prefetch double buffering of K/Vt tiles.
// Key columns of P and Vt are PERMUTED by col' = (c&15)*4 + (c>>4) so each
// lane's 4 P-values per row are contiguous -> packed b64 store (PV k-sum is
// invariant under a consistent permutation of the summation index).
// exp2 via __builtin_amdgcn_exp2f (bare v_exp_f32); P rounded half-up.
// LDS 34816 B. Per-wave P buffer; no Q/P aliasing.
// ---------------------------------------------------------------------------
__global__ __launch_bounds__(256)
void attn_mfma(const u16* __restrict__ qw, const u16* __restrict__ kw,
               const u16* __restrict__ vt, u16* __restrict__ attnb)
{
    __shared__ u16 Qs[64 * 68];     // Q tile [row][d] (dead after hoist)
    __shared__ u16 Ks[64 * 68];     // [key][d], natural key order
    __shared__ u16 Vts[64 * 68];    // [dv][key'], permuted key order
    __shared__ u16 Ps[4][16 * 68];  // per-wave P tile [row][key'], permuted

    const int tid = threadIdx.x;
    const int lane = tid & 63;
    const int wv = tid >> 6;
    const int lane15 = lane & 15, quad = lane >> 4;
    const int bh = blockIdx.x;
    const int q0 = blockIdx.y * 64;
    const size_t base = (size_t)bh * SEQ * DK;   // qw/kw [s][dk], vt [dk][s]

    const int lr = tid >> 3;             // 0..31: staging row
    const int lc = (tid & 7) * 8;        // staging col group (8 cols)
    const int vbase = (lc & 15) * 4 + (lc >> 4);   // permuted col base

    // stage Q tile 64x64
#pragma unroll
    for (int i = 0; i < 2; ++i) {
        const int flat = tid + i * 256;
        const int r = flat >> 3, c = (flat & 7) * 8;
        uint4 v = *(const uint4*)&qw[base + (size_t)(q0 + r) * DK + c];
        st8(&Qs[r * 68 + c], v.x, v.y);
        st8(&Qs[r * 68 + c + 4], v.z, v.w);
    }
    __syncthreads();

    // hoist Q fragments; wave's q-rows = q0 + wv*16 + 0..15
    bf16x8 qa[2];
#pragma unroll
    for (int kk = 0; kk < 2; ++kk)
        qa[kk] = ld8x2(&Qs[(wv * 16 + lane15) * 68 + kk * 32 + quad * 8]);

    u16* Pw = &Ps[wv][0];

    f32x4 o_acc[4];
    float lpart[4];
#pragma unroll
    for (int nd = 0; nd < 4; ++nd) o_acc[nd] = (f32x4)0.f;
#pragma unroll
    for (int r = 0; r < 4; ++r) lpart[r] = 0.f;

    // stage tile 0: K natural, Vt permuted columns
#pragma unroll
    for (int i = 0; i < 2; ++i) {
        const int r = lr + i * 32;
        uint4 kv = *(const uint4*)&kw[base + (size_t)r * DK + lc];
        st8(&Ks[r * 68 + lc], kv.x, kv.y);
        st8(&Ks[r * 68 + lc + 4], kv.z, kv.w);
        union { uint4 u; u16 s[8]; } vu;
        vu.u = *(const uint4*)&vt[base + (size_t)r * SEQ + lc];
#pragma unroll
        for (int j = 0; j < 8; ++j)
            Vts[r * 68 + vbase + 4 * j] = vu.s[j];
    }
    __syncthreads();

    for (int c0 = 0; c0 < SEQ; c0 += 64) {
        // prefetch next tile into registers (overlaps with compute below)
        uint4 kpre[2], vpre[2];
        const bool more = (c0 + 64 < SEQ);
        if (more) {
#pragma unroll
            for (int i = 0; i < 2; ++i) {
                const int r = lr + i * 32;
                kpre[i] = *(const uint4*)&kw[base + (size_t)(c0 + 64 + r) * DK + lc];
                vpre[i] = *(const uint4*)&vt[base + (size_t)r * SEQ + c0 + 64 + lc];
            }
        }

        // QK^T: 16 q-rows x 64 keys (q pre-scaled by log2e/sqrt(dk))
        f32x4 s_acc[4];
#pragma unroll
        for (int ni = 0; ni < 4; ++ni) s_acc[ni] = (f32x4)0.f;
#pragma unroll
        for (int ni = 0; ni < 4; ++ni)
#pragma unroll
            for (int kk = 0; kk < 2; ++kk) {
                bf16x8 kb = ld8x2(&Ks[(ni * 16 + lane15) * 68 + kk * 32 + quad * 8]);
                s_acc[ni] = __builtin_amdgcn_mfma_f32_16x16x32_bf16(
                    qa[kk], kb, s_acc[ni], 0, 0, 0);
            }

        // linear softmax: p = exp2(s); pack 4 per row (permuted cols) -> b64
#pragma unroll
        for (int r = 0; r < 4; ++r) {
            unsigned int u[4];
#pragma unroll
            for (int ni = 0; ni < 4; ++ni) {
                const float p = __builtin_amdgcn_exp2f(s_acc[ni][r]);
                lpart[r] += p;
                u[ni] = __float_as_uint(p) + 0x8000u;   // half-up round
            }
            const unsigned int lo = __builtin_amdgcn_perm(u[1], u[0], 0x07060302u);
            const unsigned int hi = __builtin_amdgcn_perm(u[3], u[2], 0x07060302u);
            st8(&Pw[(quad * 4 + r) * 68 + lane15 * 4], lo, hi);
        }

        // PV: o += P[16x64'] x V[64'x64] (in-wave P roundtrip, no barrier)
        bf16x8 pa[2];
#pragma unroll
        for (int kk = 0; kk < 2; ++kk)
            pa[kk] = ld8x2(&Pw[lane15 * 68 + kk * 32 + quad * 8]);
#pragma unroll
        for (int nd = 0; nd < 4; ++nd)
#pragma unroll
            for (int kk = 0; kk < 2; ++kk) {
                bf16x8 vb = ld8x2(&Vts[(nd * 16 + lane15) * 68 + kk * 32 + quad * 8]);
                o_acc[nd] = __builtin_amdgcn_mfma_f32_16x16x32_bf16(
                    pa[kk], vb, o_acc[nd], 0, 0, 0);
            }
        __syncthreads();   // everyone done reading Ks/Vts

        if (more) {
#pragma unroll
            for (int i = 0; i < 2; ++i) {
                const int r = lr + i * 32;
                st8(&Ks[r * 68 + lc], kpre[i].x, kpre[i].y);
                st8(&Ks[r * 68 + lc + 4], kpre[i].z, kpre[i].w);
                union { uint4 u; u16 s[8]; } vu;
                vu.u = vpre[i];
#pragma unroll
                for (int j = 0; j < 8; ++j)
                    Vts[r * 68 + vbase + 4 * j] = vu.s[j];
            }
        }
        __syncthreads();   // new tile visible to all waves
    }

    // epilogue: one cross-lane reduction of the deferred row sums
#pragma unroll
    for (int r = 0; r < 4; ++r) {
        float l = lpart[r];
        l += __shfl_xor(l, 1);
        l += __shfl_xor(l, 2);
        l += __shfl_xor(l, 4);
        l += __shfl_xor(l, 8);
        lpart[r] = 1.f / l;
    }

    const int b_ = bh >> 4, h = bh & 15;
#pragma unroll
    for (int r = 0; r < 4; ++r) {
        const int srow = q0 + wv * 16 + quad * 4 + r;
        const float inv = lpart[r];
#pragma unroll
        for (int nd = 0; nd < 4; ++nd)
            attnb[((size_t)b_ * SEQ + srow) * DM + h * DK + nd * 16 + lane15] =
                f2bf(o_acc[nd][r] * inv);
    }
}

// ---------------------------------------------------------------------------
extern "C" void kernel_launch(void* const* d_in, const int* in_sizes, int n_in,
                              void* d_out, int out_size, void* d_ws, size_t ws_size,
                              hipStream_t stream)
{
    const float* Q  = (const float*)d_in[0];
    const float* K  = (const float*)d_in[1];
    const float* V  = (const float*)d_in[2];
    const float* Wq = (const float*)d_in[3];
    const float* bq = (const float*)d_in[4];
    const float* Wk = (const float*)d_in[5];
    const float* bk = (const float*)d_in[6];
    const float* Wv = (const float*)d_in[7];
    const float* bv = (const float*)d_in[8];
    const float* Wo = (const float*)d_in[9];
    const float* bo = (const float*)d_in[10];
    float* out = (float*)d_out;

    const size_t MB = 1024 * 1024;
    char* w8 = (char*)d_ws;
    u16* Qbf = (u16*)(w8 + 0 * MB);      // 8 MB (aliased as attn out later)
    u16* Kbf = (u16*)(w8 + 8 * MB);
    u16* Vbf = (u16*)(w8 + 16 * MB);
    u16* Wtq = (u16*)(w8 + 24 * MB);     // 2 MB each
    u16* Wtk = (u16*)(w8 + 26 * MB);
    u16* Wtv = (u16*)(w8 + 28 * MB);
    u16* Wto = (u16*)(w8 + 30 * MB);
    u16* qw  = (u16*)(w8 + 32 * MB);     // 8 MB [bh][s][dk]
    u16* kw  = (u16*)(w8 + 40 * MB);     // 8 MB [bh][s][dk]
    u16* vtw = (u16*)(w8 + 48 * MB);     // 8 MB [bh][dk][s] (direct from qkv)
    u16* attnb = Qbf;                    // alias: Qbf dead after qkv_gemm

    cvt_in<<<dim3(2048, 1, 3), 256, 0, stream>>>(Q, K, V, Qbf, Kbf, Vbf);
    cvt_wt<<<dim3(16, 16, 4), 256, 0, stream>>>(Wq, Wk, Wv, Wo,
                                                Wtq, Wtk, Wtv, Wto);
    qkv_gemm<<<dim3(32, 8, 3), 256, 0, stream>>>(Qbf, Kbf, Vbf, Wtq, Wtk, Wtv,
                                                 bq, bk, bv, qw, kw, vtw);
    attn_mfma<<<dim3(32, 32), 256, 0, stream>>>(qw, kw, vtw, attnb);
    out_gemm<<<dim3(32, 16), 256, 0, stream>>>(attnb, Wto, bo, out);
}

// Round 7
// 249.884 us; speedup vs baseline: 1.0460x; 1.0460x over previous
//
#include <hip/hip_runtime.h>
#include <math.h>

#define SEQ   2048
#define DM    1024
#define NH    16
#define DK    64
#define MTOT  4096
// q pre-scale: 1/sqrt(64) * log2(e), so softmax runs in exp2 domain
#define QSCALE 0.18033688011112043f

typedef __bf16 bf16x8 __attribute__((ext_vector_type(8)));
typedef float  f32x4  __attribute__((ext_vector_type(4)));
typedef unsigned short u16;
typedef unsigned long long u64;

// RNE float->bf16 (finite inputs)
__device__ __forceinline__ u16 f2bf(float f) {
    unsigned int u = __float_as_uint(f);
    u += 0x7fff + ((u >> 16) & 1);
    return (u16)(u >> 16);
}

// async global->LDS, 16B per lane; LDS dest = base + lane*16 (HW semantics)
__device__ __forceinline__ void async16(const void* g, void* l) {
    __builtin_amdgcn_global_load_lds(
        (const __attribute__((address_space(1))) unsigned int*)(unsigned long long)g,
        (__attribute__((address_space(3))) unsigned int*)(unsigned int)(unsigned long long)l,
        16, 0, 0);
}

// Alias-safe accessors (memcpy => universal aliasing; same ds codegen)
__device__ __forceinline__ bf16x8 ld16(const u16* p) {        // 16B aligned
    bf16x8 v;
    __builtin_memcpy(&v, p, 16);
    return v;
}
__device__ __forceinline__ bf16x8 ld8x2(const u16* p) {       // 8B aligned
    union { u64 q[2]; bf16x8 v; } u;
    __builtin_memcpy(&u.q[0], p, 8);
    __builtin_memcpy(&u.q[1], p + 4, 8);
    return u.v;
}
__device__ __forceinline__ void st8(u16* p, unsigned int lo, unsigned int hi) {
    u64 q = ((u64)hi << 32) | lo;
    __builtin_memcpy(p, &q, 8);
}

// ---------------------------------------------------------------------------
// fp32 -> bf16 elementwise (Q, K, V inputs), 8 elems/thread
// ---------------------------------------------------------------------------
__global__ __launch_bounds__(256)
void cvt_in(const float* __restrict__ Q, const float* __restrict__ K,
            const float* __restrict__ V, u16* __restrict__ Qb,
            u16* __restrict__ Kb, u16* __restrict__ Vb)
{
    const float* src; u16* dst;
    if (blockIdx.z == 0)      { src = Q; dst = Qb; }
    else if (blockIdx.z == 1) { src = K; dst = Kb; }
    else                      { src = V; dst = Vb; }
    const size_t i = ((size_t)blockIdx.x * 256 + threadIdx.x) * 8;
    float4 a = *(const float4*)&src[i];
    float4 b = *(const float4*)&src[i + 4];
    uint4 o;
    o.x = (unsigned)f2bf(a.x) | ((unsigned)f2bf(a.y) << 16);
    o.y = (unsigned)f2bf(a.z) | ((unsigned)f2bf(a.w) << 16);
    o.z = (unsigned)f2bf(b.x) | ((unsigned)f2bf(b.y) << 16);
    o.w = (unsigned)f2bf(b.z) | ((unsigned)f2bf(b.w) << 16);
    *(uint4*)&dst[i] = o;
}

// ---------------------------------------------------------------------------
// W [k][n] fp32 -> Wt [n][k] bf16 (64x64 tiles via LDS)
// ---------------------------------------------------------------------------
__global__ __launch_bounds__(256)
void cvt_wt(const float* __restrict__ Wq, const float* __restrict__ Wk,
            const float* __restrict__ Wv, const float* __restrict__ Wo,
            u16* __restrict__ Tq, u16* __restrict__ Tk,
            u16* __restrict__ Tv, u16* __restrict__ To)
{
    const float* W; u16* Wt;
    if (blockIdx.z == 0)      { W = Wq; Wt = Tq; }
    else if (blockIdx.z == 1) { W = Wk; Wt = Tk; }
    else if (blockIdx.z == 2) { W = Wv; Wt = Tv; }
    else                      { W = Wo; Wt = To; }
    __shared__ float Ts[64][65];
    const int t = threadIdx.x;
    const int k0 = blockIdx.x * 64, n0 = blockIdx.y * 64;
#pragma unroll
    for (int p = 0; p < 4; ++p) {
        const int flat = t + p * 256;
        const int r = flat >> 4, c4 = (flat & 15) * 4;
        float4 v = *(const float4*)&W[(size_t)(k0 + r) * DM + n0 + c4];
        Ts[r][c4 + 0] = v.x; Ts[r][c4 + 1] = v.y;
        Ts[r][c4 + 2] = v.z; Ts[r][c4 + 3] = v.w;
    }
    __syncthreads();
#pragma unroll
    for (int p = 0; p < 2; ++p) {
        const int flat = t + p * 256;
        const int n = flat >> 3, kc = (flat & 7) * 8;
        uint4 o;
        o.x = (unsigned)f2bf(Ts[kc + 0][n]) | ((unsigned)f2bf(Ts[kc + 1][n]) << 16);
        o.y = (unsigned)f2bf(Ts[kc + 2][n]) | ((unsigned)f2bf(Ts[kc + 3][n]) << 16);
        o.z = (unsigned)f2bf(Ts[kc + 4][n]) | ((unsigned)f2bf(Ts[kc + 5][n]) << 16);
        o.w = (unsigned)f2bf(Ts[kc + 6][n]) | ((unsigned)f2bf(Ts[kc + 7][n]) << 16);
        *(uint4*)&Wt[(size_t)(n0 + n) * DM + k0 + kc] = o;
    }
}

// ---------------------------------------------------------------------------
// bf16 MFMA GEMM: C[m][n] = A[m][k] * Wt[n][k]^T + bias
// 128x128 tile, BK=64 as TWO 32-wide panels (keeps BK=32's conflict-free
// stride-16-dword LDS layout; halves barrier count). 4 waves 2x2.
// SCATTER=1: bf16 out [bh][s][dk] (with scale); SCATTER=2: bf16 out
// [bh][dk][s] (transposed); SCATTER=0: fp32 out [m][n].
// ---------------------------------------------------------------------------
template <int SCATTER>
__device__ __forceinline__ void gemm_core(const u16* __restrict__ A,
                                          const u16* __restrict__ Wt,
                                          const float* __restrict__ bias,
                                          void* __restrict__ Out, float scale)
{
    __shared__ u16 As[2][128 * 32];   // 8 KB per panel
    __shared__ u16 Bs[2][128 * 32];

    const int tid = threadIdx.x;
    const int lane = tid & 63;
    const int wv = __builtin_amdgcn_readfirstlane(tid >> 6);
    const int wm = wv >> 1, wn = wv & 1;
    const int lane15 = lane & 15, quad = lane >> 4;
    const int row0 = blockIdx.x * 128, col0 = blockIdx.y * 128;

    const int arow = lane >> 2;          // 0..15
    const int acol = (lane & 3) * 8;     // bf16 col within 32

    f32x4 acc[4][4];
#pragma unroll
    for (int i = 0; i < 4; ++i)
#pragma unroll
        for (int j = 0; j < 4; ++j) acc[i][j] = (f32x4)0.f;

    for (int k0 = 0; k0 < DM; k0 += 64) {
#pragma unroll
        for (int p = 0; p < 2; ++p) {
#pragma unroll
            for (int cc = 0; cc < 2; ++cc) {
                const int c = 2 * wv + cc;
                async16(&A[(size_t)(row0 + c * 16 + arow) * DM + k0 + p * 32 + acol],
                        &As[p][c * 512]);
                async16(&Wt[(size_t)(col0 + c * 16 + arow) * DM + k0 + p * 32 + acol],
                        &Bs[p][c * 512]);
            }
        }
        __syncthreads();

#pragma unroll
        for (int kk = 0; kk < 2; ++kk) {
            bf16x8 af[4];
#pragma unroll
            for (int mi = 0; mi < 4; ++mi)
                af[mi] = ld16(&As[kk][(wm * 64 + mi * 16 + lane15) * 32 + quad * 8]);
#pragma unroll
            for (int ni = 0; ni < 4; ++ni) {
                bf16x8 bfrag = ld16(&Bs[kk][(wn * 64 + ni * 16 + lane15) * 32 + quad * 8]);
#pragma unroll
                for (int mi = 0; mi < 4; ++mi)
                    acc[mi][ni] = __builtin_amdgcn_mfma_f32_16x16x32_bf16(
                        af[mi], bfrag, acc[mi][ni], 0, 0, 0);
            }
        }
        __syncthreads();
    }

#pragma unroll
    for (int mi = 0; mi < 4; ++mi) {
        const int mbase = row0 + wm * 64 + mi * 16 + quad * 4;
#pragma unroll
        for (int ni = 0; ni < 4; ++ni) {
            const int n = col0 + wn * 64 + ni * 16 + lane15;
            const float bz = bias[n];
            if (SCATTER == 1) {
                const int h = n >> 6, dk = n & 63;
#pragma unroll
                for (int r = 0; r < 4; ++r) {
                    const int mm = mbase + r;
                    const int b_ = mm >> 11, s = mm & 2047;
                    ((u16*)Out)[(((size_t)(b_ * NH + h)) * SEQ + s) * DK + dk] =
                        f2bf((acc[mi][ni][r] + bz) * scale);
                }
            } else if (SCATTER == 2) {
                const int h = n >> 6, dk = n & 63;
                const int b_ = mbase >> 11, s0 = mbase & 2047;
                u64 q = (u64)f2bf((acc[mi][ni][0] + bz) * scale)
                      | ((u64)f2bf((acc[mi][ni][1] + bz) * scale) << 16)
                      | ((u64)f2bf((acc[mi][ni][2] + bz) * scale) << 32)
                      | ((u64)f2bf((acc[mi][ni][3] + bz) * scale) << 48);
                u16* dst = (u16*)Out +
                    (((size_t)(b_ * NH + h)) * DK + dk) * SEQ + s0;
                __builtin_memcpy(dst, &q, 8);
            } else {
#pragma unroll
                for (int r = 0; r < 4; ++r) {
                    const int mm = mbase + r;
                    ((float*)Out)[(size_t)mm * DM + n] = acc[mi][ni][r] + bz;
                }
            }
        }
    }
}

__global__ __launch_bounds__(256)
void qkv_gemm(const u16* __restrict__ Qb, const u16* __restrict__ Kb,
              const u16* __restrict__ Vb,
              const u16* __restrict__ Tq, const u16* __restrict__ Tk,
              const u16* __restrict__ Tv,
              const float* __restrict__ bq, const float* __restrict__ bk,
              const float* __restrict__ bv,
              u16* __restrict__ qw, u16* __restrict__ kw, u16* __restrict__ vtw)
{
    if (blockIdx.z == 0)      gemm_core<1>(Qb, Tq, bq, qw, QSCALE);
    else if (blockIdx.z == 1) gemm_core<1>(Kb, Tk, bk, kw, 1.0f);
    else                      gemm_core<2>(Vb, Tv, bv, vtw, 1.0f);
}

// ---------------------------------------------------------------------------
// Output GEMM: 128x64 tiles, BK=64 via two 32-wide panels. 512 blocks.
// ---------------------------------------------------------------------------
__global__ __launch_bounds__(256)
void out_gemm(const u16* __restrict__ A, const u16* __restrict__ Wt,
              const float* __restrict__ bias, float* __restrict__ Out)
{
    __shared__ u16 As[2][128 * 32];
    __shared__ u16 Bs[2][64 * 32];

    const int tid = threadIdx.x;
    const int lane = tid & 63;
    const int wv = __builtin_amdgcn_readfirstlane(tid >> 6);
    const int wm = wv >> 1, wn = wv & 1;
    const int lane15 = lane & 15, quad = lane >> 4;
    const int row0 = blockIdx.x * 128, col0 = blockIdx.y * 64;

    const int arow = lane >> 2;
    const int acol = (lane & 3) * 8;

    f32x4 acc[4][2];
#pragma unroll
    for (int i = 0; i < 4; ++i)
#pragma unroll
        for (int j = 0; j < 2; ++j) acc[i][j] = (f32x4)0.f;

    for (int k0 = 0; k0 < DM; k0 += 64) {
#pragma unroll
        for (int p = 0; p < 2; ++p) {
#pragma unroll
            for (int cc = 0; cc < 2; ++cc) {
                const int c = 2 * wv + cc;
                async16(&A[(size_t)(row0 + c * 16 + arow) * DM + k0 + p * 32 + acol],
                        &As[p][c * 512]);
            }
            async16(&Wt[(size_t)(col0 + wv * 16 + arow) * DM + k0 + p * 32 + acol],
                    &Bs[p][wv * 512]);
        }
        __syncthreads();

#pragma unroll
        for (int kk = 0; kk < 2; ++kk) {
            bf16x8 af[4];
#pragma unroll
            for (int mi = 0; mi < 4; ++mi)
                af[mi] = ld16(&As[kk][(wm * 64 + mi * 16 + lane15) * 32 + quad * 8]);
#pragma unroll
            for (int ni = 0; ni < 2; ++ni) {
                bf16x8 bfrag = ld16(&Bs[kk][(wn * 32 + ni * 16 + lane15) * 32 + quad * 8]);
#pragma unroll
                for (int mi = 0; mi < 4; ++mi)
                    acc[mi][ni] = __builtin_amdgcn_mfma_f32_16x16x32_bf16(
                        af[mi], bfrag, acc[mi][ni], 0, 0, 0);
            }
        }
        __syncthreads();
    }

#pragma unroll
    for (int mi = 0; mi < 4; ++mi) {
        const int mbase = row0 + wm * 64 + mi * 16 + quad * 4;
#pragma unroll
        for (int ni = 0; ni < 2; ++ni) {
            const int n = col0 + wn * 32 + ni * 16 + lane15;
            const float bz = bias[n];
#pragma unroll
            for (int r = 0; r < 4; ++r)
                Out[(size_t)(mbase + r) * DM + n] = acc[mi][ni][r] + bz;
        }
    }
}

// ---------------------------------------------------------------------------
// Flash attention, bf16 MFMA, linear softmax, SPLIT-K over keys (partials
// add exactly since there is no running max). Block = 2 waves x 32 q-rows
// = 64 q-rows, one 1024-key half; 16 key-tiles of 64.
// Grid 2048 flat blocks of 128 thr; LDS 25.5 KB -> 6 blocks/CU.
// Block decode is XCD-swizzled: each XCD works on 4 heads (2 MB K/V in L2).
// Q fragments load directly from global (no Q LDS). Register-prefetch
// double buffering of K/Vt tiles. Partial O (unnormalized, bf16) + partial
// l (fp32) written to workspace; attn_combine adds halves and normalizes.
// ---------------------------------------------------------------------------
__global__ __launch_bounds__(128, 3)
void attn_mfma(const u16* __restrict__ qw, const u16* __restrict__ kw,
               const u16* __restrict__ vt, u16* __restrict__ opart,
               float* __restrict__ lw)
{
    __shared__ u16 Ks[64 * 68];     // [key][d], natural key order
    __shared__ u16 Vts[64 * 68];    // [dv][key'], permuted key order
    __shared__ u16 Ps[2][32 * 68];  // per-wave P tile [row][key'], permuted

    const int tid = threadIdx.x;
    const int lane = tid & 63;
    const int wv = tid >> 6;
    const int lane15 = lane & 15, quad = lane >> 4;

    // XCD-swizzled decode: xcd = flat%8 -> 4 heads per XCD
    const int flat = blockIdx.x;
    const int xcd = flat & 7;
    const int rest = flat >> 3;              // 0..255
    const int bh = xcd * 4 + (rest & 3);
    const int qt = (rest >> 2) & 31;
    const int ks = rest >> 7;                // key half 0/1
    const int q0 = qt * 64;
    const int c0beg = ks * 1024;
    const size_t base = (size_t)bh * SEQ * DK;

    // Q fragments directly from global; wave rows = q0 + wv*32 + mi*16 + ...
    bf16x8 qa[2][2];
#pragma unroll
    for (int mi = 0; mi < 2; ++mi)
#pragma unroll
        for (int kk = 0; kk < 2; ++kk)
            qa[mi][kk] = ld16(&qw[base +
                (size_t)(q0 + wv * 32 + mi * 16 + lane15) * DK + kk * 32 + quad * 8]);

    u16* Pw = &Ps[wv][0];

    f32x4 o_acc[2][4];
    float lpart[8];
#pragma unroll
    for (int mi = 0; mi < 2; ++mi)
#pragma unroll
        for (int nd = 0; nd < 4; ++nd) o_acc[mi][nd] = (f32x4)0.f;
#pragma unroll
    for (int r = 0; r < 8; ++r) lpart[r] = 0.f;

    // staging map: 128 thr cover 64 rows x 64 cols; thread -> row sr, col half
    const int sr = tid >> 1;                 // 0..63
    const int sh = (tid & 1) * 32;           // col half base (elements)

    // stage tile 0: K natural, Vt permuted cols (col' = (c&15)*4 + (c>>4))
#pragma unroll
    for (int j = 0; j < 4; ++j) {
        const int c = sh + j * 8;
        const int cb = (c & 15) * 4 + (c >> 4);
        uint4 kv = *(const uint4*)&kw[base + (size_t)(c0beg + sr) * DK + c];
        st8(&Ks[sr * 68 + c], kv.x, kv.y);
        st8(&Ks[sr * 68 + c + 4], kv.z, kv.w);
        union { uint4 u; u16 s[8]; } vu;
        vu.u = *(const uint4*)&vt[base + (size_t)sr * SEQ + c0beg + c];
#pragma unroll
        for (int e = 0; e < 8; ++e) Vts[sr * 68 + cb + 4 * e] = vu.s[e];
    }
    __syncthreads();

    for (int it = 0; it < 16; ++it) {
        const int c0 = c0beg + it * 64;
        // prefetch next tile into registers
        uint4 kpre[4], vpre[4];
        const bool more = (it < 15);
        if (more) {
#pragma unroll
            for (int j = 0; j < 4; ++j) {
                const int c = sh + j * 8;
                kpre[j] = *(const uint4*)&kw[base + (size_t)(c0 + 64 + sr) * DK + c];
                vpre[j] = *(const uint4*)&vt[base + (size_t)sr * SEQ + c0 + 64 + c];
            }
        }

        // QK^T: 32 q-rows x 64 keys
        f32x4 s_acc[2][4];
#pragma unroll
        for (int mi = 0; mi < 2; ++mi)
#pragma unroll
            for (int ni = 0; ni < 4; ++ni) s_acc[mi][ni] = (f32x4)0.f;
#pragma unroll
        for (int ni = 0; ni < 4; ++ni)
#pragma unroll
            for (int kk = 0; kk < 2; ++kk) {
                bf16x8 kb = ld8x2(&Ks[(ni * 16 + lane15) * 68 + kk * 32 + quad * 8]);
#pragma unroll
                for (int mi = 0; mi < 2; ++mi)
                    s_acc[mi][ni] = __builtin_amdgcn_mfma_f32_16x16x32_bf16(
                        qa[mi][kk], kb, s_acc[mi][ni], 0, 0, 0);
            }

        // linear softmax: p = exp2(s); pack 4 per row (permuted cols) -> b64
#pragma unroll
        for (int mi = 0; mi < 2; ++mi)
#pragma unroll
            for (int r = 0; r < 4; ++r) {
                unsigned int u[4];
#pragma unroll
                for (int ni = 0; ni < 4; ++ni) {
                    const float p = __builtin_amdgcn_exp2f(s_acc[mi][ni][r]);
                    lpart[mi * 4 + r] += p;
                    u[ni] = __float_as_uint(p) + 0x8000u;   // half-up round
                }
                const unsigned int lo = __builtin_amdgcn_perm(u[1], u[0], 0x07060302u);
                const unsigned int hi = __builtin_amdgcn_perm(u[3], u[2], 0x07060302u);
                st8(&Pw[(mi * 16 + quad * 4 + r) * 68 + lane15 * 4], lo, hi);
            }

        // PV: o += P[32x64'] x V[64'x64] (in-wave P roundtrip, no barrier)
        bf16x8 pa[2][2];
#pragma unroll
        for (int mi = 0; mi < 2; ++mi)
#pragma unroll
            for (int kk = 0; kk < 2; ++kk)
                pa[mi][kk] = ld8x2(&Pw[(mi * 16 + lane15) * 68 + kk * 32 + quad * 8]);
#pragma unroll
        for (int nd = 0; nd < 4; ++nd)
#pragma unroll
            for (int kk = 0; kk < 2; ++kk) {
                bf16x8 vb = ld8x2(&Vts[(nd * 16 + lane15) * 68 + kk * 32 + quad * 8]);
#pragma unroll
                for (int mi = 0; mi < 2; ++mi)
                    o_acc[mi][nd] = __builtin_amdgcn_mfma_f32_16x16x32_bf16(
                        pa[mi][kk], vb, o_acc[mi][nd], 0, 0, 0);
            }
        __syncthreads();   // both waves done reading Ks/Vts

        if (more) {
#pragma unroll
            for (int j = 0; j < 4; ++j) {
                const int c = sh + j * 8;
                const int cb = (c & 15) * 4 + (c >> 4);
                st8(&Ks[sr * 68 + c], kpre[j].x, kpre[j].y);
                st8(&Ks[sr * 68 + c + 4], kpre[j].z, kpre[j].w);
                union { uint4 u; u16 s[8]; } vu;
                vu.u = vpre[j];
#pragma unroll
                for (int e = 0; e < 8; ++e) Vts[sr * 68 + cb + 4 * e] = vu.s[e];
            }
        }
        __syncthreads();   // new tile visible
    }

    // epilogue: store UNNORMALIZED partial O (bf16) + partial l (fp32)
    const size_t obase = ((size_t)(ks * 32 + bh)) * SEQ;   // row slab in opart
#pragma unroll
    for (int mi = 0; mi < 2; ++mi)
#pragma unroll
        for (int r = 0; r < 4; ++r) {
            const int s = q0 + wv * 32 + mi * 16 + quad * 4 + r;
            float l = lpart[mi * 4 + r];
            l += __shfl_xor(l, 1);
            l += __shfl_xor(l, 2);
            l += __shfl_xor(l, 4);
            l += __shfl_xor(l, 8);
            if (lane15 == 0)
                lw[(size_t)(ks * 32 + bh) * SEQ + s] = l;
#pragma unroll
            for (int nd = 0; nd < 4; ++nd)
                opart[(obase + s) * DK + nd * 16 + lane15] = f2bf(o_acc[mi][nd][r]);
        }
}

// ---------------------------------------------------------------------------
// Combine the two key-half partials: O = (O0 + O1) / (l0 + l1), bf16 out.
// ---------------------------------------------------------------------------
__global__ __launch_bounds__(256)
void attn_combine(const u16* __restrict__ opart, const float* __restrict__ lw,
                  u16* __restrict__ attnb)
{
    const int flat = blockIdx.x * 256 + threadIdx.x;   // < 524288
    const int dv = (flat & 7) * 8;
    const int s  = (flat >> 3) & 2047;
    const int bh = flat >> 14;
    const size_t i0 = ((size_t)bh * SEQ + s) * DK + dv;
    const size_t i1 = i0 + (size_t)32 * SEQ * DK;
    uint4 a = *(const uint4*)&opart[i0];
    uint4 b = *(const uint4*)&opart[i1];
    const float l = lw[(size_t)bh * SEQ + s] + lw[(size_t)(32 + bh) * SEQ + s];
    const float inv = 1.f / l;
    unsigned int au[4] = {a.x, a.y, a.z, a.w};
    unsigned int bu[4] = {b.x, b.y, b.z, b.w};
    unsigned int ou[4];
#pragma unroll
    for (int j = 0; j < 4; ++j) {
        const float e0 = __uint_as_float(au[j] << 16) + __uint_as_float(bu[j] << 16);
        const float e1 = __uint_as_float(au[j] & 0xffff0000u) +
                         __uint_as_float(bu[j] & 0xffff0000u);
        ou[j] = (unsigned)f2bf(e0 * inv) | ((unsigned)f2bf(e1 * inv) << 16);
    }
    const int b_ = bh >> 4, h = bh & 15;
    uint4 o; o.x = ou[0]; o.y = ou[1]; o.z = ou[2]; o.w = ou[3];
    *(uint4*)&attnb[((size_t)b_ * SEQ + s) * DM + h * DK + dv] = o;
}

// ---------------------------------------------------------------------------
extern "C" void kernel_launch(void* const* d_in, const int* in_sizes, int n_in,
                              void* d_out, int out_size, void* d_ws, size_t ws_size,
                              hipStream_t stream)
{
    const float* Q  = (const float*)d_in[0];
    const float* K  = (const float*)d_in[1];
    const float* V  = (const float*)d_in[2];
    const float* Wq = (const float*)d_in[3];
    const float* bq = (const float*)d_in[4];
    const float* Wk = (const float*)d_in[5];
    const float* bk = (const float*)d_in[6];
    const float* Wv = (const float*)d_in[7];
    const float* bv = (const float*)d_in[8];
    const float* Wo = (const float*)d_in[9];
    const float* bo = (const float*)d_in[10];
    float* out = (float*)d_out;

    const size_t MB = 1024 * 1024;
    char* w8 = (char*)d_ws;
    u16* Qbf = (u16*)(w8 + 0 * MB);      // 8 MB (aliased as attn out later)
    u16* Kbf = (u16*)(w8 + 8 * MB);      // dead after qkv -> opart
    u16* Vbf = (u16*)(w8 + 16 * MB);     // dead after qkv -> opart
    u16* Wtq = (u16*)(w8 + 24 * MB);     // 2 MB each
    u16* Wtk = (u16*)(w8 + 26 * MB);
    u16* Wtv = (u16*)(w8 + 28 * MB);
    u16* Wto = (u16*)(w8 + 30 * MB);     // alive until out_gemm
    u16* qw  = (u16*)(w8 + 32 * MB);     // 8 MB [bh][s][dk]
    u16* kw  = (u16*)(w8 + 40 * MB);     // 8 MB [bh][s][dk]
    u16* vtw = (u16*)(w8 + 48 * MB);     // 8 MB [bh][dk][s] (direct from qkv)
    u16* opart = Kbf;                    // 16 MB @ 8..24: partial O (bf16)
    float* lwb = (float*)(w8 + 56 * MB); // 512 KB: partial l (fp32)
    u16* attnb = Qbf;                    // alias: Qbf dead after qkv_gemm

    cvt_in<<<dim3(2048, 1, 3), 256, 0, stream>>>(Q, K, V, Qbf, Kbf, Vbf);
    cvt_wt<<<dim3(16, 16, 4), 256, 0, stream>>>(Wq, Wk, Wv, Wo,
                                                Wtq, Wtk, Wtv, Wto);
    qkv_gemm<<<dim3(32, 8, 3), 256, 0, stream>>>(Qbf, Kbf, Vbf, Wtq, Wtk, Wtv,
                                                 bq, bk, bv, qw, kw, vtw);
    attn_mfma<<<2048, 128, 0, stream>>>(qw, kw, vtw, opart, lwb);
    attn_combine<<<2048, 256, 0, stream>>>(opart, lwb, attnb);
    out_gemm<<<dim3(32, 16), 256, 0, stream>>>(attnb, Wto, bo, out);
}

// Round 8
// 226.642 us; speedup vs baseline: 1.1533x; 1.1025x over previous
//
#include <hip/hip_runtime.h>
#include <math.h>

#define SEQ   2048
#define DM    1024
#define NH    16
#define DK    64
#define MTOT  4096
// q pre-scale: 1/sqrt(64) * log2(e), so softmax runs in exp2 domain
#define QSCALE 0.18033688011112043f

typedef __bf16 bf16x8 __attribute__((ext_vector_type(8)));
typedef float  f32x4  __attribute__((ext_vector_type(4)));
typedef unsigned short u16;
typedef unsigned long long u64;

// RNE float->bf16 (finite inputs)
__device__ __forceinline__ u16 f2bf(float f) {
    unsigned int u = __float_as_uint(f);
    u += 0x7fff + ((u >> 16) & 1);
    return (u16)(u >> 16);
}

// async global->LDS, 16B per lane; LDS dest = base + lane*16 (HW semantics)
__device__ __forceinline__ void async16(const void* g, void* l) {
    __builtin_amdgcn_global_load_lds(
        (const __attribute__((address_space(1))) unsigned int*)(unsigned long long)g,
        (__attribute__((address_space(3))) unsigned int*)(unsigned int)(unsigned long long)l,
        16, 0, 0);
}

// Alias-safe accessors (memcpy => universal aliasing; same ds codegen)
__device__ __forceinline__ bf16x8 ld16(const u16* p) {        // 16B aligned
    bf16x8 v;
    __builtin_memcpy(&v, p, 16);
    return v;
}
__device__ __forceinline__ void st8(u16* p, unsigned int lo, unsigned int hi) {
    u64 q = ((u64)hi << 32) | lo;
    __builtin_memcpy(p, &q, 8);
}

// ---------------------------------------------------------------------------
// fp32 -> bf16 elementwise (Q, K, V inputs), 8 elems/thread
// ---------------------------------------------------------------------------
__global__ __launch_bounds__(256)
void cvt_in(const float* __restrict__ Q, const float* __restrict__ K,
            const float* __restrict__ V, u16* __restrict__ Qb,
            u16* __restrict__ Kb, u16* __restrict__ Vb)
{
    const float* src; u16* dst;
    if (blockIdx.z == 0)      { src = Q; dst = Qb; }
    else if (blockIdx.z == 1) { src = K; dst = Kb; }
    else                      { src = V; dst = Vb; }
    const size_t i = ((size_t)blockIdx.x * 256 + threadIdx.x) * 8;
    float4 a = *(const float4*)&src[i];
    float4 b = *(const float4*)&src[i + 4];
    uint4 o;
    o.x = (unsigned)f2bf(a.x) | ((unsigned)f2bf(a.y) << 16);
    o.y = (unsigned)f2bf(a.z) | ((unsigned)f2bf(a.w) << 16);
    o.z = (unsigned)f2bf(b.x) | ((unsigned)f2bf(b.y) << 16);
    o.w = (unsigned)f2bf(b.z) | ((unsigned)f2bf(b.w) << 16);
    *(uint4*)&dst[i] = o;
}

// ---------------------------------------------------------------------------
// W [k][n] fp32 -> Wt [n][k] bf16 (64x64 tiles via LDS)
// ---------------------------------------------------------------------------
__global__ __launch_bounds__(256)
void cvt_wt(const float* __restrict__ Wq, const float* __restrict__ Wk,
            const float* __restrict__ Wv, const float* __restrict__ Wo,
            u16* __restrict__ Tq, u16* __restrict__ Tk,
            u16* __restrict__ Tv, u16* __restrict__ To)
{
    const float* W; u16* Wt;
    if (blockIdx.z == 0)      { W = Wq; Wt = Tq; }
    else if (blockIdx.z == 1) { W = Wk; Wt = Tk; }
    else if (blockIdx.z == 2) { W = Wv; Wt = Tv; }
    else                      { W = Wo; Wt = To; }
    __shared__ float Ts[64][65];
    const int t = threadIdx.x;
    const int k0 = blockIdx.x * 64, n0 = blockIdx.y * 64;
#pragma unroll
    for (int p = 0; p < 4; ++p) {
        const int flat = t + p * 256;
        const int r = flat >> 4, c4 = (flat & 15) * 4;
        float4 v = *(const float4*)&W[(size_t)(k0 + r) * DM + n0 + c4];
        Ts[r][c4 + 0] = v.x; Ts[r][c4 + 1] = v.y;
        Ts[r][c4 + 2] = v.z; Ts[r][c4 + 3] = v.w;
    }
    __syncthreads();
#pragma unroll
    for (int p = 0; p < 2; ++p) {
        const int flat = t + p * 256;
        const int n = flat >> 3, kc = (flat & 7) * 8;
        uint4 o;
        o.x = (unsigned)f2bf(Ts[kc + 0][n]) | ((unsigned)f2bf(Ts[kc + 1][n]) << 16);
        o.y = (unsigned)f2bf(Ts[kc + 2][n]) | ((unsigned)f2bf(Ts[kc + 3][n]) << 16);
        o.z = (unsigned)f2bf(Ts[kc + 4][n]) | ((unsigned)f2bf(Ts[kc + 5][n]) << 16);
        o.w = (unsigned)f2bf(Ts[kc + 6][n]) | ((unsigned)f2bf(Ts[kc + 7][n]) << 16);
        *(uint4*)&Wt[(size_t)(n0 + n) * DM + k0 + kc] = o;
    }
}

// ---------------------------------------------------------------------------
// bf16 MFMA GEMM (R5-proven m97 structure): C = A * Wt^T + bias
// 128x128 tile, BK=32, 4 waves 2x2, each wave 4x4 of 16x16x32 MFMA.
// SCATTER=1: bf16 out [bh][s][dk] (with scale); SCATTER=2: bf16 out
// [bh][dk][s] (transposed); SCATTER=0: fp32 out [m][n].
// ---------------------------------------------------------------------------
template <int SCATTER>
__device__ __forceinline__ void gemm_core(const u16* __restrict__ A,
                                          const u16* __restrict__ Wt,
                                          const float* __restrict__ bias,
                                          void* __restrict__ Out, float scale)
{
    __shared__ u16 As[128 * 32];
    __shared__ u16 Bs[128 * 32];

    const int tid = threadIdx.x;
    const int lane = tid & 63;
    const int wv = __builtin_amdgcn_readfirstlane(tid >> 6);
    const int wm = wv >> 1, wn = wv & 1;
    const int lane15 = lane & 15, quad = lane >> 4;
    const int row0 = blockIdx.x * 128, col0 = blockIdx.y * 128;

    const int arow = lane >> 2;          // 0..15
    const int acol = (lane & 3) * 8;     // bf16 col within 32

    f32x4 acc[4][4];
#pragma unroll
    for (int i = 0; i < 4; ++i)
#pragma unroll
        for (int j = 0; j < 4; ++j) acc[i][j] = (f32x4)0.f;

    for (int k0 = 0; k0 < DM; k0 += 32) {
#pragma unroll
        for (int cc = 0; cc < 2; ++cc) {
            const int c = 2 * wv + cc;
            async16(&A[(size_t)(row0 + c * 16 + arow) * DM + k0 + acol],
                    &As[c * 512]);
            async16(&Wt[(size_t)(col0 + c * 16 + arow) * DM + k0 + acol],
                    &Bs[c * 512]);
        }
        __syncthreads();

        bf16x8 af[4];
#pragma unroll
        for (int mi = 0; mi < 4; ++mi)
            af[mi] = ld16(&As[(wm * 64 + mi * 16 + lane15) * 32 + quad * 8]);
#pragma unroll
        for (int ni = 0; ni < 4; ++ni) {
            bf16x8 bfrag = ld16(&Bs[(wn * 64 + ni * 16 + lane15) * 32 + quad * 8]);
#pragma unroll
            for (int mi = 0; mi < 4; ++mi)
                acc[mi][ni] = __builtin_amdgcn_mfma_f32_16x16x32_bf16(
                    af[mi], bfrag, acc[mi][ni], 0, 0, 0);
        }
        __syncthreads();
    }

#pragma unroll
    for (int mi = 0; mi < 4; ++mi) {
        const int mbase = row0 + wm * 64 + mi * 16 + quad * 4;
#pragma unroll
        for (int ni = 0; ni < 4; ++ni) {
            const int n = col0 + wn * 64 + ni * 16 + lane15;
            const float bz = bias[n];
            if (SCATTER == 1) {
                const int h = n >> 6, dk = n & 63;
#pragma unroll
                for (int r = 0; r < 4; ++r) {
                    const int mm = mbase + r;
                    const int b_ = mm >> 11, s = mm & 2047;
                    ((u16*)Out)[(((size_t)(b_ * NH + h)) * SEQ + s) * DK + dk] =
                        f2bf((acc[mi][ni][r] + bz) * scale);
                }
            } else if (SCATTER == 2) {
                const int h = n >> 6, dk = n & 63;
                const int b_ = mbase >> 11, s0 = mbase & 2047;
                u64 q = (u64)f2bf((acc[mi][ni][0] + bz) * scale)
                      | ((u64)f2bf((acc[mi][ni][1] + bz) * scale) << 16)
                      | ((u64)f2bf((acc[mi][ni][2] + bz) * scale) << 32)
                      | ((u64)f2bf((acc[mi][ni][3] + bz) * scale) << 48);
                u16* dst = (u16*)Out +
                    (((size_t)(b_ * NH + h)) * DK + dk) * SEQ + s0;
                __builtin_memcpy(dst, &q, 8);
            } else {
#pragma unroll
                for (int r = 0; r < 4; ++r) {
                    const int mm = mbase + r;
                    ((float*)Out)[(size_t)mm * DM + n] = acc[mi][ni][r] + bz;
                }
            }
        }
    }
}

__global__ __launch_bounds__(256)
void qkv_gemm(const u16* __restrict__ Qb, const u16* __restrict__ Kb,
              const u16* __restrict__ Vb,
              const u16* __restrict__ Tq, const u16* __restrict__ Tk,
              const u16* __restrict__ Tv,
              const float* __restrict__ bq, const float* __restrict__ bk,
              const float* __restrict__ bv,
              u16* __restrict__ qw, u16* __restrict__ kw, u16* __restrict__ vtw)
{
    if (blockIdx.z == 0)      gemm_core<1>(Qb, Tq, bq, qw, QSCALE);
    else if (blockIdx.z == 1) gemm_core<1>(Kb, Tk, bk, kw, 1.0f);
    else                      gemm_core<2>(Vb, Tv, bv, vtw, 1.0f);
}

// ---------------------------------------------------------------------------
// Output GEMM: 128x64 tiles, BK=32 (R5-proven). 512 blocks (2/CU).
// ---------------------------------------------------------------------------
__global__ __launch_bounds__(256)
void out_gemm(const u16* __restrict__ A, const u16* __restrict__ Wt,
              const float* __restrict__ bias, float* __restrict__ Out)
{
    __shared__ u16 As[128 * 32];
    __shared__ u16 Bs[64 * 32];

    const int tid = threadIdx.x;
    const int lane = tid & 63;
    const int wv = __builtin_amdgcn_readfirstlane(tid >> 6);
    const int wm = wv >> 1, wn = wv & 1;
    const int lane15 = lane & 15, quad = lane >> 4;
    const int row0 = blockIdx.x * 128, col0 = blockIdx.y * 64;

    const int arow = lane >> 2;
    const int acol = (lane & 3) * 8;

    f32x4 acc[4][2];
#pragma unroll
    for (int i = 0; i < 4; ++i)
#pragma unroll
        for (int j = 0; j < 2; ++j) acc[i][j] = (f32x4)0.f;

    for (int k0 = 0; k0 < DM; k0 += 32) {
#pragma unroll
        for (int cc = 0; cc < 2; ++cc) {
            const int c = 2 * wv + cc;
            async16(&A[(size_t)(row0 + c * 16 + arow) * DM + k0 + acol],
                    &As[c * 512]);
        }
        async16(&Wt[(size_t)(col0 + wv * 16 + arow) * DM + k0 + acol],
                &Bs[wv * 512]);
        __syncthreads();

        bf16x8 af[4];
#pragma unroll
        for (int mi = 0; mi < 4; ++mi)
            af[mi] = ld16(&As[(wm * 64 + mi * 16 + lane15) * 32 + quad * 8]);
#pragma unroll
        for (int ni = 0; ni < 2; ++ni) {
            bf16x8 bfrag = ld16(&Bs[(wn * 32 + ni * 16 + lane15) * 32 + quad * 8]);
#pragma unroll
            for (int mi = 0; mi < 4; ++mi)
                acc[mi][ni] = __builtin_amdgcn_mfma_f32_16x16x32_bf16(
                    af[mi], bfrag, acc[mi][ni], 0, 0, 0);
        }
        __syncthreads();
    }

#pragma unroll
    for (int mi = 0; mi < 4; ++mi) {
        const int mbase = row0 + wm * 64 + mi * 16 + quad * 4;
#pragma unroll
        for (int ni = 0; ni < 2; ++ni) {
            const int n = col0 + wn * 32 + ni * 16 + lane15;
            const float bz = bias[n];
#pragma unroll
            for (int r = 0; r < 4; ++r)
                Out[(size_t)(mbase + r) * DM + n] = acc[mi][ni][r] + bz;
        }
    }
}

// ---------------------------------------------------------------------------
// Flash attention, bf16 MFMA, linear softmax, split-K over key halves.
// KEY TRICK: compute S^T = K*Q^T (operands swapped). C-layout then holds,
// per lane, P[q = mi*16 + lane15][key = 16*ki + 4*quad + r]. With the key
// permutation sigma(kk,quad,j) = 16*(2kk+(j>>2)) + 4*quad + (j&3), that set
// equals exactly the keys the lane's PV A-fragment must supply -> P is
// repacked IN-REGISTER (exp2 + v_perm), no LDS roundtrip, no cross-lane.
// V is staged into LDS with sigma's slot order (4 consecutive keys stay
// contiguous -> plain b64 stores). O comes out in the standard C-layout.
// Double-buffered K/V tiles -> ONE barrier per tile; prefetch loads issue at
// tile start, LDS writes after PV (max vmcnt slack).
// Block = 2 waves x 32 q-rows; grid 2048 (XCD-swizzled); LDS 36864 B.
// ---------------------------------------------------------------------------
__global__ __launch_bounds__(128, 2)
void attn_mfma(const u16* __restrict__ qw, const u16* __restrict__ kw,
               const u16* __restrict__ vt, u16* __restrict__ opart,
               float* __restrict__ lw)
{
    __shared__ u16 Ks[2][64 * 72];    // [key][d], natural, stride 72 (16B rows)
    __shared__ u16 Vts[2][64 * 72];   // [dv][key-slot], sigma order

    const int tid = threadIdx.x;
    const int lane = tid & 63;
    const int wv = tid >> 6;
    const int lane15 = lane & 15, quad = lane >> 4;

    // XCD-swizzled decode: 4 heads per XCD (2 MB K/V resident in L2)
    const int flat = blockIdx.x;
    const int xcd = flat & 7;
    const int rest = flat >> 3;              // 0..255
    const int bh = xcd * 4 + (rest & 3);
    const int qt = (rest >> 2) & 31;
    const int ks = rest >> 7;                // key half 0/1
    const int q0 = qt * 64;
    const int c0beg = ks * 1024;
    const size_t base = (size_t)bh * SEQ * DK;

    // Q fragments (B-operand of S^T): wave rows = q0 + wv*32 + mi*16 + lane15
    bf16x8 qb[2][2];
#pragma unroll
    for (int mi = 0; mi < 2; ++mi)
#pragma unroll
        for (int kk = 0; kk < 2; ++kk)
            qb[mi][kk] = ld16(&qw[base +
                (size_t)(q0 + wv * 32 + mi * 16 + lane15) * DK + kk * 32 + quad * 8]);

    f32x4 o_acc[2][4];
    float lpart[2];
#pragma unroll
    for (int mi = 0; mi < 2; ++mi) {
        lpart[mi] = 0.f;
#pragma unroll
        for (int nd = 0; nd < 4; ++nd) o_acc[mi][nd] = (f32x4)0.f;
    }

    // staging map: 128 thr cover 64 rows x 64 cols (two 32-col halves)
    const int sr = tid >> 1;                 // 0..63
    const int sh = (tid & 1) * 32;           // col half base

    // V slot bases for the 4 col-groups (sigma-contiguous 4-key runs)
    int vslot[4];
#pragma unroll
    for (int j = 0; j < 4; ++j) {
        const int c8 = sh + j * 8;
        const int a = c8 >> 4, b = (c8 >> 2) & 3;
        vslot[j] = (a >> 1) * 32 + b * 8 + (a & 1) * 4;
    }

    // stage tile 0 into buffer 0
#pragma unroll
    for (int j = 0; j < 4; ++j) {
        const int c8 = sh + j * 8;
        uint4 kv = *(const uint4*)&kw[base + (size_t)(c0beg + sr) * DK + c8];
        st8(&Ks[0][sr * 72 + c8], kv.x, kv.y);
        st8(&Ks[0][sr * 72 + c8 + 4], kv.z, kv.w);
        uint4 vv = *(const uint4*)&vt[base + (size_t)sr * SEQ + c0beg + c8];
        st8(&Vts[0][sr * 72 + vslot[j]], vv.x, vv.y);
        st8(&Vts[0][sr * 72 + vslot[j] + 8], vv.z, vv.w);
    }
    __syncthreads();

    for (int it = 0; it < 16; ++it) {
        const int cur = it & 1;
        const u16* Kc = &Ks[cur][0];
        const u16* Vc = &Vts[cur][0];

        // prefetch next tile into registers
        uint4 kpre[4], vpre[4];
        const bool more = (it < 15);
        if (more) {
            const int cn = c0beg + (it + 1) * 64;
#pragma unroll
            for (int j = 0; j < 4; ++j) {
                const int c8 = sh + j * 8;
                kpre[j] = *(const uint4*)&kw[base + (size_t)(cn + sr) * DK + c8];
                vpre[j] = *(const uint4*)&vt[base + (size_t)sr * SEQ + cn + c8];
            }
        }

        // S^T = K * Q^T : rows = keys (ki), cols = q
        f32x4 sT[2][4];
#pragma unroll
        for (int mi = 0; mi < 2; ++mi)
#pragma unroll
            for (int ki = 0; ki < 4; ++ki) sT[mi][ki] = (f32x4)0.f;
#pragma unroll
        for (int ki = 0; ki < 4; ++ki)
#pragma unroll
            for (int kk = 0; kk < 2; ++kk) {
                bf16x8 ka = ld16(&Kc[(ki * 16 + lane15) * 72 + kk * 32 + quad * 8]);
#pragma unroll
                for (int mi = 0; mi < 2; ++mi)
                    sT[mi][ki] = __builtin_amdgcn_mfma_f32_16x16x32_bf16(
                        ka, qb[mi][kk], sT[mi][ki], 0, 0, 0);
            }

        // softmax + IN-REGISTER repack to PV A-fragments
        bf16x8 pa[2][2];
#pragma unroll
        for (int mi = 0; mi < 2; ++mi) {
            unsigned int ulo[4], uhi[4];
#pragma unroll
            for (int ki = 0; ki < 4; ++ki) {
                unsigned int u[4];
#pragma unroll
                for (int r = 0; r < 4; ++r) {
                    const float p = __builtin_amdgcn_exp2f(sT[mi][ki][r]);
                    lpart[mi] += p;
                    u[r] = __float_as_uint(p) + 0x8000u;   // half-up round
                }
                ulo[ki] = __builtin_amdgcn_perm(u[1], u[0], 0x07060302u);
                uhi[ki] = __builtin_amdgcn_perm(u[3], u[2], 0x07060302u);
            }
#pragma unroll
            for (int kk = 0; kk < 2; ++kk) {
                union { uint4 u; bf16x8 v; } pk;
                pk.u.x = ulo[2 * kk];     pk.u.y = uhi[2 * kk];
                pk.u.z = ulo[2 * kk + 1]; pk.u.w = uhi[2 * kk + 1];
                pa[mi][kk] = pk.v;
            }
        }

        // PV: O += P * V  (V in sigma slot order matches pa's k-slots)
#pragma unroll
        for (int nd = 0; nd < 4; ++nd)
#pragma unroll
            for (int kk = 0; kk < 2; ++kk) {
                bf16x8 vb = ld16(&Vc[(nd * 16 + lane15) * 72 + kk * 32 + quad * 8]);
#pragma unroll
                for (int mi = 0; mi < 2; ++mi)
                    o_acc[mi][nd] = __builtin_amdgcn_mfma_f32_16x16x32_bf16(
                        pa[mi][kk], vb, o_acc[mi][nd], 0, 0, 0);
            }

        // write prefetched tile into the other buffer (its readers finished
        // at the previous barrier), then one barrier to publish + retire cur
        if (more) {
            const int nxt = cur ^ 1;
#pragma unroll
            for (int j = 0; j < 4; ++j) {
                const int c8 = sh + j * 8;
                st8(&Ks[nxt][sr * 72 + c8], kpre[j].x, kpre[j].y);
                st8(&Ks[nxt][sr * 72 + c8 + 4], kpre[j].z, kpre[j].w);
                st8(&Vts[nxt][sr * 72 + vslot[j]], vpre[j].x, vpre[j].y);
                st8(&Vts[nxt][sr * 72 + vslot[j] + 8], vpre[j].z, vpre[j].w);
            }
        }
        __syncthreads();
    }

    // epilogue: l lives per-lane at q = mi*16 + lane15; complete across quads
    const size_t rowbase = (size_t)(ks * 32 + bh) * SEQ;
#pragma unroll
    for (int mi = 0; mi < 2; ++mi) {
        float l = lpart[mi];
        l += __shfl_xor(l, 16);
        l += __shfl_xor(l, 32);
        if (quad == 0)
            lw[rowbase + q0 + wv * 32 + mi * 16 + lane15] = l;
    }
    // unnormalized partial O: q = mi*16 + quad*4 + r, dv = nd*16 + lane15
#pragma unroll
    for (int mi = 0; mi < 2; ++mi)
#pragma unroll
        for (int r = 0; r < 4; ++r) {
            const int s = q0 + wv * 32 + mi * 16 + quad * 4 + r;
#pragma unroll
            for (int nd = 0; nd < 4; ++nd)
                opart[(rowbase + s) * DK + nd * 16 + lane15] = f2bf(o_acc[mi][nd][r]);
        }
}

// ---------------------------------------------------------------------------
// Combine the two key-half partials: O = (O0 + O1) / (l0 + l1), bf16 out.
// ---------------------------------------------------------------------------
__global__ __launch_bounds__(256)
void attn_combine(const u16* __restrict__ opart, const float* __restrict__ lw,
                  u16* __restrict__ attnb)
{
    const int flat = blockIdx.x * 256 + threadIdx.x;   // < 524288
    const int dv = (flat & 7) * 8;
    const int s  = (flat >> 3) & 2047;
    const int bh = flat >> 14;
    const size_t i0 = ((size_t)bh * SEQ + s) * DK + dv;
    const size_t i1 = i0 + (size_t)32 * SEQ * DK;
    uint4 a = *(const uint4*)&opart[i0];
    uint4 b = *(const uint4*)&opart[i1];
    const float l = lw[(size_t)bh * SEQ + s] + lw[(size_t)(32 + bh) * SEQ + s];
    const float inv = 1.f / l;
    unsigned int au[4] = {a.x, a.y, a.z, a.w};
    unsigned int bu[4] = {b.x, b.y, b.z, b.w};
    unsigned int ou[4];
#pragma unroll
    for (int j = 0; j < 4; ++j) {
        const float e0 = __uint_as_float(au[j] << 16) + __uint_as_float(bu[j] << 16);
        const float e1 = __uint_as_float(au[j] & 0xffff0000u) +
                         __uint_as_float(bu[j] & 0xffff0000u);
        ou[j] = (unsigned)f2bf(e0 * inv) | ((unsigned)f2bf(e1 * inv) << 16);
    }
    const int b_ = bh >> 4, h = bh & 15;
    uint4 o; o.x = ou[0]; o.y = ou[1]; o.z = ou[2]; o.w = ou[3];
    *(uint4*)&attnb[((size_t)b_ * SEQ + s) * DM + h * DK + dv] = o;
}

// ---------------------------------------------------------------------------
extern "C" void kernel_launch(void* const* d_in, const int* in_sizes, int n_in,
                              void* d_out, int out_size, void* d_ws, size_t ws_size,
                              hipStream_t stream)
{
    const float* Q  = (const float*)d_in[0];
    const float* K  = (const float*)d_in[1];
    const float* V  = (const float*)d_in[2];
    const float* Wq = (const float*)d_in[3];
    const float* bq = (const float*)d_in[4];
    const float* Wk = (const float*)d_in[5];
    const float* bk = (const float*)d_in[6];
    const float* Wv = (const float*)d_in[7];
    const float* bv = (const float*)d_in[8];
    const float* Wo = (const float*)d_in[9];
    const float* bo = (const float*)d_in[10];
    float* out = (float*)d_out;

    const size_t MB = 1024 * 1024;
    char* w8 = (char*)d_ws;
    u16* Qbf = (u16*)(w8 + 0 * MB);      // 8 MB (aliased as attn out later)
    u16* Kbf = (u16*)(w8 + 8 * MB);      // dead after qkv -> opart
    u16* Vbf = (u16*)(w8 + 16 * MB);     // dead after qkv -> opart
    u16* Wtq = (u16*)(w8 + 24 * MB);     // 2 MB each
    u16* Wtk = (u16*)(w8 + 26 * MB);
    u16* Wtv = (u16*)(w8 + 28 * MB);
    u16* Wto = (u16*)(w8 + 30 * MB);     // alive until out_gemm
    u16* qw  = (u16*)(w8 + 32 * MB);     // 8 MB [bh][s][dk]
    u16* kw  = (u16*)(w8 + 40 * MB);     // 8 MB [bh][s][dk]
    u16* vtw = (u16*)(w8 + 48 * MB);     // 8 MB [bh][dk][s] (direct from qkv)
    u16* opart = Kbf;                    // 16 MB @ 8..24: partial O (bf16)
    float* lwb = (float*)(w8 + 56 * MB); // 512 KB: partial l (fp32)
    u16* attnb = Qbf;                    // alias: Qbf dead after qkv_gemm

    cvt_in<<<dim3(2048, 1, 3), 256, 0, stream>>>(Q, K, V, Qbf, Kbf, Vbf);
    cvt_wt<<<dim3(16, 16, 4), 256, 0, stream>>>(Wq, Wk, Wv, Wo,
                                                Wtq, Wtk, Wtv, Wto);
    qkv_gemm<<<dim3(32, 8, 3), 256, 0, stream>>>(Qbf, Kbf, Vbf, Wtq, Wtk, Wtv,
                                                 bq, bk, bv, qw, kw, vtw);
    attn_mfma<<<2048, 128, 0, stream>>>(qw, kw, vtw, opart, lwb);
    attn_combine<<<2048, 256, 0, stream>>>(opart, lwb, attnb);
    out_gemm<<<dim3(32, 16), 256, 0, stream>>>(attnb, Wto, bo, out);
}